// Round 1
// baseline (5586.961 us; speedup 1.0000x reference)
//
#include <hip/hip_runtime.h>
#include <hip/hip_bf16.h>

typedef __bf16 bf8 __attribute__((ext_vector_type(8)));   // 16 B
typedef float  f32x4 __attribute__((ext_vector_type(4)));

#define TT 512
#define BBATCH 64
#define IDIM 1024
#define HDIM 1024
#define G4 4096

__device__ __forceinline__ float sigf(float x) {
  x = fminf(fmaxf(x, -30.f), 30.f);
  return 1.f / (1.f + __expf(-x));
}
__device__ __forceinline__ float tanh_(float x) {
  x = fminf(fmaxf(x, -15.f), 15.f);
  float e = __expf(2.f * x);
  return (e - 1.f) / (e + 1.f);
}

__device__ __forceinline__ f32x4 MFMA(bf8 a, bf8 b, f32x4 c) {
  return __builtin_amdgcn_mfma_f32_16x16x32_bf16(a, b, c, 0, 0, 0);
}

// ---------------------------------------------------------------------------
// Convert weights: WxT[n][k] = W{g}_x[k][j], WhT[n][k] = W{g}_h[k][j]
// (n = g*1024 + j, gate order a,i,f,o).  Also bias[n] = b{g}[j].
// ---------------------------------------------------------------------------
__global__ void k_convert(const float* __restrict__ wa, const float* __restrict__ wi,
                          const float* __restrict__ wf, const float* __restrict__ wo,
                          const float* __restrict__ ha, const float* __restrict__ hi,
                          const float* __restrict__ hf, const float* __restrict__ ho,
                          const float* __restrict__ b0, const float* __restrict__ b1,
                          const float* __restrict__ b2, const float* __restrict__ b3,
                          __bf16* __restrict__ WxT, __bf16* __restrict__ WhT,
                          float* __restrict__ bias) {
  int gid = blockIdx.x * 256 + threadIdx.x;
  if (gid < G4) {
    int g = gid >> 10, j = gid & 1023;
    const float* bs = (g == 0) ? b0 : (g == 1) ? b1 : (g == 2) ? b2 : b3;
    bias[gid] = bs[j];
  }
  if (gid < G4 * IDIM) {
    int n = gid >> 10, k = gid & 1023;
    int g = n >> 10, j = n & 1023;
    const float* s = (g == 0) ? wa : (g == 1) ? wi : (g == 2) ? wf : wo;
    WxT[gid] = (__bf16)s[k * 1024 + j];
  } else {
    int idx = gid - G4 * IDIM;
    if (idx < G4 * HDIM) {
      int n = idx >> 10, k = idx & 1023;
      int g = n >> 10, j = n & 1023;
      const float* s = (g == 0) ? ha : (g == 1) ? hi : (g == 2) ? hf : ho;
      WhT[idx] = (__bf16)s[k * 1024 + j];
    }
  }
}

// ---------------------------------------------------------------------------
// Phase 1: Xg[m][n] = sum_k X[m][k] * WxT[n][k] + bias[n]
// 128x128 tile, BK=32, 4 waves, each wave 64x64 (4x4 frags of 16x16x32 bf16).
// A is fp32 (converted to bf16 during staging).
// ---------------------------------------------------------------------------
__global__ __launch_bounds__(256) void k_gemm_xg(const float* __restrict__ A,
                                                 const __bf16* __restrict__ BT,
                                                 const float* __restrict__ bias,
                                                 float* __restrict__ C, int M) {
  __shared__ __bf16 As[128][40];
  __shared__ __bf16 Bs[128][40];
  int tid = threadIdx.x, lane = tid & 63, w = tid >> 6;
  int m0 = blockIdx.y * 128, n0 = blockIdx.x * 128;
  int wr = (w >> 1) * 64, wc = (w & 1) * 64;

  f32x4 acc[4][4] = {};

  int sm = tid >> 1;           // 0..127
  int sk = (tid & 1) * 16;     // 0 or 16
  bool aval = (m0 + sm) < M;
  const float*  Ap = A + (size_t)(m0 + sm) * IDIM + sk;
  const __bf16* Bp = BT + (size_t)(n0 + sm) * IDIM + sk;

  float4 a0, a1, a2, a3;
  bf8 rb0, rb1;
  auto loadA = [&](int kt) {
    if (aval) {
      const float4* p = (const float4*)(Ap + kt * 32);
      a0 = p[0]; a1 = p[1]; a2 = p[2]; a3 = p[3];
    } else {
      a0 = a1 = a2 = a3 = make_float4(0.f, 0.f, 0.f, 0.f);
    }
  };
  auto loadB = [&](int kt) {
    const bf8* p = (const bf8*)(Bp + kt * 32);
    rb0 = p[0]; rb1 = p[1];
  };
  loadA(0); loadB(0);

  for (int kt = 0; kt < 32; ++kt) {
    __syncthreads();
    // stage (convert A to bf16)
    {
      bf8 v, u;
      v[0]=(__bf16)a0.x; v[1]=(__bf16)a0.y; v[2]=(__bf16)a0.z; v[3]=(__bf16)a0.w;
      v[4]=(__bf16)a1.x; v[5]=(__bf16)a1.y; v[6]=(__bf16)a1.z; v[7]=(__bf16)a1.w;
      u[0]=(__bf16)a2.x; u[1]=(__bf16)a2.y; u[2]=(__bf16)a2.z; u[3]=(__bf16)a2.w;
      u[4]=(__bf16)a3.x; u[5]=(__bf16)a3.y; u[6]=(__bf16)a3.z; u[7]=(__bf16)a3.w;
      *(bf8*)&As[sm][sk]     = v;
      *(bf8*)&As[sm][sk + 8] = u;
      *(bf8*)&Bs[sm][sk]     = rb0;
      *(bf8*)&Bs[sm][sk + 8] = rb1;
    }
    if (kt + 1 < 32) { loadA(kt + 1); loadB(kt + 1); }
    __syncthreads();

    int row = lane & 15, kq = (lane >> 4) * 8;
    bf8 af[4], bfv[4];
#pragma unroll
    for (int r = 0; r < 4; ++r) af[r]  = *(const bf8*)&As[wr + r * 16 + row][kq];
#pragma unroll
    for (int c = 0; c < 4; ++c) bfv[c] = *(const bf8*)&Bs[wc + c * 16 + row][kq];
#pragma unroll
    for (int r = 0; r < 4; ++r)
#pragma unroll
      for (int c = 0; c < 4; ++c)
        acc[r][c] = MFMA(af[r], bfv[c], acc[r][c]);
  }

  // epilogue
  int cj = lane & 15, hi4 = (lane >> 4) * 4;
#pragma unroll
  for (int c = 0; c < 4; ++c) {
    int col = n0 + wc + c * 16 + cj;
    float bc = bias[col];
#pragma unroll
    for (int r = 0; r < 4; ++r) {
#pragma unroll
      for (int q = 0; q < 4; ++q) {
        int rr = wr + r * 16 + hi4 + q;
        if (m0 + rr < M)
          C[(size_t)(m0 + rr) * G4 + col] = acc[r][c][q] + bc;
      }
    }
  }
}

// ---------------------------------------------------------------------------
// Phase 2: one timestep.
// grid = 256 blocks, block = 4 h-cols (16 gathered G-cols: c = g*4 + jj).
// G_rec = h_prev @ Wh (bf16 MFMA, waves split K), then gates + state update.
// ---------------------------------------------------------------------------
__global__ __launch_bounds__(256) void k_step(const float* __restrict__ Xg_t,
                                              const __bf16* __restrict__ WhT,
                                              const __bf16* __restrict__ hp,
                                              __bf16* __restrict__ hn,
                                              float* __restrict__ S,
                                              float* __restrict__ out_t,
                                              int first) {
  __shared__ __bf16 As[64][136];
  __shared__ __bf16 Bs[16][136];
  __shared__ float Gs[4][64][16];
  int tid = threadIdx.x, lane = tid & 63, w = tid >> 6;
  int hc0 = blockIdx.x * 4;

  f32x4 acc[4] = {};

  if (!first) {
    int ab = tid >> 2, akg = (tid & 3) * 32;       // A-tile: [64][128]
    const __bf16* Aps = hp + ab * HDIM + akg;
    int bn = tid >> 4, bkg = (tid & 15) * 8;       // B-tile: [16][128]
    int gcol = (bn >> 2) * 1024 + hc0 + (bn & 3);
    const __bf16* Bps = WhT + (size_t)gcol * HDIM + bkg;

    bf8 ra0, ra1, ra2, ra3, rbv;
    auto ld = [&](int ko) {
      const bf8* p = (const bf8*)(Aps + ko * 128);
      ra0 = p[0]; ra1 = p[1]; ra2 = p[2]; ra3 = p[3];
      rbv = *(const bf8*)(Bps + ko * 128);
    };
    ld(0);
    for (int ko = 0; ko < 8; ++ko) {
      __syncthreads();
      *(bf8*)&As[ab][akg]      = ra0;
      *(bf8*)&As[ab][akg + 8]  = ra1;
      *(bf8*)&As[ab][akg + 16] = ra2;
      *(bf8*)&As[ab][akg + 24] = ra3;
      *(bf8*)&Bs[bn][bkg]      = rbv;
      if (ko < 7) ld(ko + 1);
      __syncthreads();

      int row = lane & 15, kq = w * 32 + (lane >> 4) * 8;
      bf8 bfv = *(const bf8*)&Bs[row][kq];
#pragma unroll
      for (int r = 0; r < 4; ++r) {
        bf8 af = *(const bf8*)&As[r * 16 + row][kq];
        acc[r] = MFMA(af, bfv, acc[r]);
      }
    }
  }

  // partial sums -> LDS
  {
    int hi4 = (lane >> 4) * 4, cj = lane & 15;
#pragma unroll
    for (int r = 0; r < 4; ++r)
#pragma unroll
      for (int q = 0; q < 4; ++q)
        Gs[w][r * 16 + hi4 + q][cj] = acc[r][q];
  }
  __syncthreads();

  // gates + state: one (b, hcl) per thread
  int b = tid >> 2, hcl = tid & 3;
  float g4[4];
#pragma unroll
  for (int g = 0; g < 4; ++g) {
    int c = g * 4 + hcl;
    float v = Gs[0][b][c] + Gs[1][b][c] + Gs[2][b][c] + Gs[3][b][c];
    g4[g] = v + Xg_t[b * G4 + g * 1024 + hc0 + hcl];
  }
  float a_ = tanh_(g4[0]);
  float i_ = sigf(g4[1]);
  float f_ = sigf(g4[2]);
  float o_ = sigf(g4[3]);
  int hcol = hc0 + hcl;
  float s_old = first ? 0.f : S[b * HDIM + hcol];
  float s_new = a_ * i_ + s_old * f_;
  float h = tanh_(s_new) * o_;
  S[b * HDIM + hcol] = s_new;
  out_t[b * HDIM + hcol] = h;
  hn[b * HDIM + hcol] = (__bf16)h;
}

// ---------------------------------------------------------------------------
extern "C" void kernel_launch(void* const* d_in, const int* in_sizes, int n_in,
                              void* d_out, int out_size, void* d_ws, size_t ws_size,
                              hipStream_t stream) {
  const float* X  = (const float*)d_in[0];
  const float* wa = (const float*)d_in[1];
  const float* wi = (const float*)d_in[2];
  const float* wf = (const float*)d_in[3];
  const float* wo = (const float*)d_in[4];
  const float* ha = (const float*)d_in[5];
  const float* hi = (const float*)d_in[6];
  const float* hf = (const float*)d_in[7];
  const float* ho = (const float*)d_in[8];
  const float* b0 = (const float*)d_in[9];
  const float* b1 = (const float*)d_in[10];
  const float* b2 = (const float*)d_in[11];
  const float* b3 = (const float*)d_in[12];
  float* out = (float*)d_out;
  char* ws = (char*)d_ws;

  size_t off = 0;
  __bf16* WxT = (__bf16*)(ws + off); off += (size_t)G4 * IDIM * 2;
  __bf16* WhT = (__bf16*)(ws + off); off += (size_t)G4 * HDIM * 2;
  float* bias = (float*)(ws + off);  off += G4 * 4;
  float* S    = (float*)(ws + off);  off += (size_t)BBATCH * HDIM * 4;
  __bf16* hb0 = (__bf16*)(ws + off); off += (size_t)BBATCH * HDIM * 2;
  __bf16* hb1 = (__bf16*)(ws + off); off += (size_t)BBATCH * HDIM * 2;
  size_t base = off;
  float* Xg = (float*)(ws + off);

  const size_t perT = (size_t)BBATCH * G4 * 4;  // 1 MB per timestep
  int Tc = 64;
  while (Tc > 1 && base + (size_t)Tc * perT > ws_size) Tc >>= 2;  // 64,16,4,1

  k_convert<<<dim3((2u * G4 * 1024) / 256), dim3(256), 0, stream>>>(
      wa, wi, wf, wo, ha, hi, hf, ho, b0, b1, b2, b3, WxT, WhT, bias);

  for (int t0 = 0; t0 < TT; t0 += Tc) {
    int M = Tc * BBATCH;
    dim3 g1(G4 / 128, (M + 127) / 128);
    k_gemm_xg<<<g1, dim3(256), 0, stream>>>(X + (size_t)t0 * BBATCH * IDIM, WxT,
                                            bias, Xg, M);
    for (int lt = 0; lt < Tc; ++lt) {
      int t = t0 + lt;
      const __bf16* hp = (t & 1) ? hb1 : hb0;  // read (unused at t=0)
      __bf16* hnx      = (t & 1) ? hb0 : hb1;  // write
      k_step<<<dim3(256), dim3(256), 0, stream>>>(
          Xg + (size_t)lt * BBATCH * G4, WhT, hp, hnx, S,
          out + (size_t)t * BBATCH * HDIM, (t == 0) ? 1 : 0);
    }
  }
}